// Round 1
// baseline (47.334 us; speedup 1.0000x reference)
//
#include <hip/hip_runtime.h>

// Median filter 1D, k=9, replicate padding, fp32.
// Input  [B=8, C=32, L=131072] flattened: 256 rows of 131072.
// Each thread: 4 outputs (float4 store), 3 aligned float4 loads.

#define CE(a, b) do { float _mn = fminf(a, b); (b) = fmaxf(a, b); (a) = _mn; } while (0)

__device__ __forceinline__ float median9(float p0, float p1, float p2,
                                         float p3, float p4, float p5,
                                         float p6, float p7, float p8) {
    // Paeth 19-compare-exchange median-of-9 network; result in p4.
    CE(p1, p2); CE(p4, p5); CE(p7, p8);
    CE(p0, p1); CE(p3, p4); CE(p6, p7);
    CE(p1, p2); CE(p4, p5); CE(p7, p8);
    CE(p0, p3); CE(p5, p8); CE(p4, p7);
    CE(p3, p6); CE(p1, p4); CE(p2, p5);
    CE(p4, p7); CE(p4, p2); CE(p6, p4);
    CE(p4, p2);
    return p4;
}

constexpr int  kL    = 131072;          // row length (power of two)
constexpr long long kTotal = 8LL * 32LL * kL;  // 33,554,432 elements
constexpr int  kPerThread = 4;

__global__ __launch_bounds__(256)
void med9_f32_kernel(const float* __restrict__ in, float* __restrict__ out) {
    long long t = (long long)blockIdx.x * blockDim.x + threadIdx.x;
    long long base = t * kPerThread;                // flattened output index
    if (base >= kTotal) return;

    int col = (int)(base & (long long)(kL - 1));    // position within row
    long long rowbase = base - col;                 // row start (flattened)
    const float* __restrict__ rin = in + rowbase;

    float v[12];
    if (col >= 4 && col + 8 <= kL) {
        // Interior fast path: 3 aligned 16B loads covering [col-4, col+7].
        float4 a = *reinterpret_cast<const float4*>(rin + col - 4);
        float4 b = *reinterpret_cast<const float4*>(rin + col);
        float4 c = *reinterpret_cast<const float4*>(rin + col + 4);
        v[0] = a.x; v[1]  = a.y; v[2]  = a.z; v[3]  = a.w;
        v[4] = b.x; v[5]  = b.y; v[6]  = b.z; v[7]  = b.w;
        v[8] = c.x; v[9]  = c.y; v[10] = c.z; v[11] = c.w;
    } else {
        // Row edge: replicate-pad via clamped scalar loads.
#pragma unroll
        for (int j = 0; j < 12; ++j) {
            int idx = col - 4 + j;
            idx = idx < 0 ? 0 : (idx > kL - 1 ? kL - 1 : idx);
            v[j] = rin[idx];
        }
    }

    float4 r;
    r.x = median9(v[0], v[1], v[2],  v[3], v[4], v[5],  v[6],  v[7],  v[8]);
    r.y = median9(v[1], v[2], v[3],  v[4], v[5], v[6],  v[7],  v[8],  v[9]);
    r.z = median9(v[2], v[3], v[4],  v[5], v[6], v[7],  v[8],  v[9],  v[10]);
    r.w = median9(v[3], v[4], v[5],  v[6], v[7], v[8],  v[9],  v[10], v[11]);

    *reinterpret_cast<float4*>(out + base) = r;
}

extern "C" void kernel_launch(void* const* d_in, const int* in_sizes, int n_in,
                              void* d_out, int out_size, void* d_ws, size_t ws_size,
                              hipStream_t stream) {
    const float* x = (const float*)d_in[0];
    // d_in[1] is kernel_size (==9); hardcoded above (host can't read device scalar
    // without breaking graph capture).
    float* out = (float*)d_out;

    long long nthreads = kTotal / kPerThread;       // 8,388,608
    int block = 256;
    int grid = (int)((nthreads + block - 1) / block);  // 32,768
    med9_f32_kernel<<<grid, block, 0, stream>>>(x, out);
}